// Round 9
// baseline (379.376 us; speedup 1.0000x reference)
//
#include <hip/hip_runtime.h>
#include <hip/hip_bf16.h>

typedef unsigned short u16;
typedef unsigned int u32;
typedef __attribute__((ext_vector_type(8))) short bf8;   // 8 bf16 (4 VGPRs)
typedef __attribute__((ext_vector_type(4))) float f4;

#define SCALE 0.125f
#define LN_EPS 1e-5f
#define WS_NEED 18485504UL

__device__ __forceinline__ float bf2f(u16 u) {
    union { u32 i; float f; } x; x.i = ((u32)u) << 16; return x.f;
}
__device__ __forceinline__ u16 f2bf(float f) {
    union { u32 i; float f; } x; x.f = f;
    u32 i = x.i;
    return (u16)((i + 0x7FFFu + ((i >> 16) & 1u)) >> 16);   // RNE
}
__device__ __forceinline__ float ldf(const void* p, long i, int isf) {
    return isf ? ((const float*)p)[i] : bf2f(((const u16*)p)[i]);
}

// ---------------- fused zero: bcnt+flag range AND AOacc+Lacc range ----------------
__global__ void k_zero2(int* __restrict__ a, int na, int* __restrict__ b, int nb) {
    int i = blockIdx.x * 256 + threadIdx.x;
    if (i < na) a[i] = 0;
    else if (i - na < nb) b[i - na] = 0;
}

// ---------------- fused: dtype detect (blocks 0..63)  ||  edge count (blocks 64..575) ----------------
__global__ void k_detcnt(const u32* __restrict__ w, int nwords, int* __restrict__ flag,
                         const int* __restrict__ EI, int* __restrict__ bcnt) {
    int bx = blockIdx.x;
    if (bx < 64) {
        int hits = 0;
        for (int i = bx * 256 + threadIdx.x; i < nwords; i += 64 * 256) {
            u32 v = w[i];
            if (((v >> 7) & 0xFFu) == 0xFFu) hits++;
            if (((v >> 23) & 0xFFu) == 0xFFu) hits++;
        }
        if (hits) atomicOr(flag, 1);
    } else {
        int e = (bx - 64) * 256 + threadIdx.x;
        int src = EI[2 * e], tgt = EI[2 * e + 1];
        atomicAdd(&bcnt[(src >> 4) * 64 + (tgt >> 6)], 1);
    }
}

// ---------------- weight transpose (z<4)  ||  small-tensor cvt (z==4) ----------------
// SB (u16): [bq 256][bk 256][bv 256][bo 256][gamma 256][beta 256][We 256][be 4]
__global__ __launch_bounds__(256) void k_transpose(const void* __restrict__ Wq,
    const void* __restrict__ Wk, const void* __restrict__ Wv, const void* __restrict__ Wo,
    u16* __restrict__ out, const int* __restrict__ flag,
    const void* bq, const void* bk, const void* bv, const void* bo,
    const void* g, const void* bt, const void* We, const void* be, u16* __restrict__ SB)
{
    __shared__ u16 tile[32][33];
    int isf = flag[0];
    if (blockIdx.z == 4) {
        if (blockIdx.x == 0 && blockIdx.y == 0) {
            int t = threadIdx.x;
            SB[0 * 256 + t] = isf ? f2bf(((const float*)bq)[t]) : ((const u16*)bq)[t];
            SB[1 * 256 + t] = isf ? f2bf(((const float*)bk)[t]) : ((const u16*)bk)[t];
            SB[2 * 256 + t] = isf ? f2bf(((const float*)bv)[t]) : ((const u16*)bv)[t];
            SB[3 * 256 + t] = isf ? f2bf(((const float*)bo)[t]) : ((const u16*)bo)[t];
            SB[4 * 256 + t] = isf ? f2bf(((const float*)g)[t])  : ((const u16*)g)[t];
            SB[5 * 256 + t] = isf ? f2bf(((const float*)bt)[t]) : ((const u16*)bt)[t];
            SB[6 * 256 + t] = isf ? f2bf(((const float*)We)[t]) : ((const u16*)We)[t];
            if (t < 4)
                SB[7 * 256 + t] = isf ? f2bf(((const float*)be)[t]) : ((const u16*)be)[t];
        }
        return;
    }
    const void* src = blockIdx.z == 0 ? Wq : blockIdx.z == 1 ? Wk : blockIdx.z == 2 ? Wv : Wo;
    u16* dst = out + blockIdx.z * 65536;
    int r0 = blockIdx.x * 32, c0 = blockIdx.y * 32;
    int lr = threadIdx.x >> 5, lc = threadIdx.x & 31;
    #pragma unroll
    for (int rr = 0; rr < 4; rr++) {
        int r = rr * 8 + lr;
        long idx = (long)(r0 + r) * 256 + c0 + lc;
        tile[r][lc] = isf ? f2bf(((const float*)src)[idx]) : ((const u16*)src)[idx];
    }
    __syncthreads();
    #pragma unroll
    for (int rr = 0; rr < 4; rr++) {
        int r = rr * 8 + lr;
        dst[(c0 + r) * 256 + r0 + lc] = tile[lc][r];
    }
}

// ---------------- scan (unchanged) ----------------
__global__ __launch_bounds__(256) void k_scan(const int* __restrict__ cntin,
                                              int* __restrict__ bptr, int* __restrict__ nextc)
{
    __shared__ int tot[256], base_l[256];
    int tid = threadIdx.x;
    int s = 0;
    int loc[64];
    #pragma unroll
    for (int j = 0; j < 64; j++) { loc[j] = cntin[tid * 64 + j]; s += loc[j]; }
    tot[tid] = s;
    __syncthreads();
    if (tid == 0) {
        int run = 0;
        for (int i = 0; i < 256; i++) { int t = tot[i]; base_l[i] = run; run += t; }
        bptr[16384] = run;
    }
    __syncthreads();
    int b = base_l[tid];
    #pragma unroll
    for (int j = 0; j < 64; j++) { bptr[tid * 64 + j] = b; nextc[tid * 64 + j] = b; b += loc[j]; }
}

// ---------------- fused: QKV GEMM (blocks 0..255)  ||  edge fill (blocks 256..767) ----------------
// Packed layouts (v8-proven; flash loads become single 1KB coalesced reads):
//   Kp[((((mt*4+h)*4+tk)*2+kw)*64 + q*16+ck)*8 + j]  <- K[row= mt*64+tk*16+ck][col= h*64+kw*32+q*8+j]
//   Vp[((((mt*4+h)*4+t2)*2+hf)*64 + q*16+c2)*8 + j]  <- V[node m= mt*64+hf*32+q*8+j][dim d= h*64+t2*16+c2]
__global__ __launch_bounds__(256) void k_qkvfill(const void* __restrict__ X,
    const u16* __restrict__ WT, const u16* __restrict__ SB,
    u16* __restrict__ Qo, u16* __restrict__ Kp, u16* __restrict__ Vp,
    const void* __restrict__ EF, const int* __restrict__ EI,
    int* __restrict__ nextc, int* __restrict__ csr_tq, float* __restrict__ csr_b,
    const int* __restrict__ flag)
{
    __shared__ float Wl[64][4];
    __shared__ float bel[4];
    int tid = threadIdx.x;
    int isf = flag[0];

    if (blockIdx.x < 256) {
        // ---- QKV GEMM (v8 body) ----
        int wave = tid >> 6, lane = tid & 63, quad = lane >> 4, c = lane & 15;
        int m0 = blockIdx.x * 16;

        bf8 af[8];
        if (isf) {
            const float* Xf = (const float*)X;
            #pragma unroll
            for (int ks = 0; ks < 8; ks++) {
                const float* p = Xf + (long)(m0 + c) * 256 + ks * 32 + quad * 8;
                f4 a = *(const f4*)p, b = *(const f4*)(p + 4);
                bf8 t;
                #pragma unroll
                for (int j = 0; j < 4; j++) { t[j] = (short)f2bf(a[j]); t[j + 4] = (short)f2bf(b[j]); }
                af[ks] = t;
            }
        } else {
            #pragma unroll
            for (int ks = 0; ks < 8; ks++)
                af[ks] = *(const bf8*)((const u16*)X + (long)(m0 + c) * 256 + ks * 32 + quad * 8);
        }

        for (int which = 0; which < 3; which++) {
            const u16* Wp = WT + which * 65536;
            const u16* bias = SB + which * 256;

            f4 acc[4];
            #pragma unroll
            for (int t = 0; t < 4; t++) acc[t] = (f4){0.f, 0.f, 0.f, 0.f};

            #pragma unroll
            for (int ks = 0; ks < 8; ks++) {
                #pragma unroll
                for (int t = 0; t < 4; t++) {
                    bf8 bfr = *(const bf8*)(Wp + (wave * 64 + t * 16 + c) * 256 + ks * 32 + quad * 8);
                    acc[t] = __builtin_amdgcn_mfma_f32_16x16x32_bf16(af[ks], bfr, acc[t], 0, 0, 0);
                }
            }
            #pragma unroll
            for (int t = 0; t < 4; t++) {
                int n = wave * 64 + t * 16 + c;
                float bb = bf2f(bias[n]);
                #pragma unroll
                for (int r = 0; r < 4; r++) {
                    int row = m0 + quad * 4 + r;
                    float v = acc[t][r] + bb;
                    u16 bv16 = f2bf(v);
                    if (which == 0) {
                        Qo[(long)row * 256 + n] = bv16;
                    } else if (which == 1) {
                        int mt = row >> 6, tk = (row >> 4) & 3, ck = row & 15;
                        int hh = n >> 6, kw = (n >> 5) & 1, q = (n >> 3) & 3, j = n & 7;
                        long idx = ((long)(((mt * 4 + hh) * 4 + tk) * 2 + kw) * 64 + q * 16 + ck) * 8 + j;
                        Kp[idx] = bv16;
                    } else {
                        int hh = n >> 6, t2 = (n >> 4) & 3, c2 = n & 15;
                        int mt = row >> 6, mo = row & 63, hf = mo >> 5, q = (mo >> 3) & 3, j = mo & 7;
                        long idx = ((long)(((mt * 4 + hh) * 4 + t2) * 2 + hf) * 64 + q * 16 + c2) * 8 + j;
                        Vp[idx] = bv16;
                    }
                }
            }
        }
    } else {
        // ---- edge-bias GEMV + bucketed fill (proven body) ----
        Wl[tid >> 2][tid & 3] = bf2f(SB[6 * 256 + tid]);
        if (tid < 4) bel[tid] = bf2f(SB[7 * 256 + tid]);
        __syncthreads();
        int e = (blockIdx.x - 256) * 256 + tid;
        int src = EI[2 * e], tgt = EI[2 * e + 1];
        float ea0 = bel[0], ea1 = bel[1], ea2 = bel[2], ea3 = bel[3];
        if (isf) {
            const float* Ff = (const float*)EF + (long)e * 64;
            for (int d0 = 0; d0 < 64; d0 += 4) {
                f4 v = *(const f4*)(Ff + d0);
                #pragma unroll
                for (int j = 0; j < 4; j++) {
                    float f = v[j];
                    ea0 += f * Wl[d0 + j][0];
                    ea1 += f * Wl[d0 + j][1];
                    ea2 += f * Wl[d0 + j][2];
                    ea3 += f * Wl[d0 + j][3];
                }
            }
        } else {
            const u16* Fb = (const u16*)EF + (long)e * 64;
            for (int d0 = 0; d0 < 64; d0 += 8) {
                bf8 v8 = *(const bf8*)(Fb + d0);
                #pragma unroll
                for (int j = 0; j < 8; j++) {
                    float f = bf2f((u16)v8[j]);
                    ea0 += f * Wl[d0 + j][0];
                    ea1 += f * Wl[d0 + j][1];
                    ea2 += f * Wl[d0 + j][2];
                    ea3 += f * Wl[d0 + j][3];
                }
            }
        }
        int bucket = (src >> 4) * 64 + (tgt >> 6);
        int pos = atomicAdd(&nextc[bucket], 1);
        csr_tq[pos] = ((src & 15) << 16) | tgt;
        f4 bb = {ea0, ea1, ea2, ea3};
        *(f4*)(csr_b + (long)pos * 4) = bb;
    }
}

// ---------------- flash v10: exact v8 per-wave body, 4-wave blocks, 20 waves/CU ----------------
// Occupancy geometry (from R5/R6/R8 evidence):
//  * 1-wave WGs cap at ~16 WG/CU (v5): more blocks never raises waves/CU.
//  * 4-wave WGs + launch_bounds(256,8) caps regs at 64 -> spill (v6).
//  * body needs ~80 unified regs; launch_bounds(256,5) caps at ~96-102 -> fits.
//  => 4-wave blocks (4 heads share qt,ks), grid (qt=256, ks=8) = 2048 blocks,
//     5 blocks/CU x 4 waves = 20 waves/CU AND per-wave work halved (8 tiles).
// Per-wave body = v8 verbatim (packed K/V loads, adj lookahead, batched csr,
// bpermute P-shuffle, no-max softmax, atomic merge). K-prefetch of R8 REVERTED
// (it spilled: VGPR 56->64, WRITE +2MB, flash 93->108).
__global__ __launch_bounds__(256, 5) void k_flash(
    const u16* __restrict__ Qb, const u16* __restrict__ Kp, const u16* __restrict__ Vp,
    const void* __restrict__ adj, const int* __restrict__ bptr,
    const int* __restrict__ csr_tq, const float* __restrict__ csr_b,
    float* __restrict__ AOacc, float* __restrict__ Lacc, const int* __restrict__ flag)
{
    __shared__ char smem[4 * 4352];                    // per-head EB f32[16][68]

    int tid = threadIdx.x;
    int h = tid >> 6, lane = tid & 63, quad = lane >> 4, c = lane & 15;
    int qt = blockIdx.x, ks = blockIdx.y;
    int n0 = qt * 16;
    int isf = flag[0];

    float (*EBs)[68] = (float(*)[68])(smem + h * 4352);

    // Q fragments (B-operand of swapped QK^T): row n0+c, k = h*64 + kw*32 + quad*8
    bf8 qf[2];
    #pragma unroll
    for (int kw = 0; kw < 2; kw++)
        qf[kw] = *(const bf8*)(Qb + (long)(n0 + c) * 256 + h * 64 + kw * 32 + quad * 8);

    float l_run = 0.f;
    f4 Oacc[4];
    #pragma unroll
    for (int t = 0; t < 4; t++) Oacc[t] = (f4){0.f, 0.f, 0.f, 0.f};

    int zr = lane >> 2, zc0 = (lane & 3) * 16;          // EB zeroing assignment
    // bpermute byte addresses (lane-constant): srcLane = quad_src*16 + c
    int addrA = ((2 * (quad & 1)) * 16 + c) * 4;        // i in {0,1}
    int addrB = addrA + 64;                             // i in {2,3} (+16 lanes)
    int selLo = quad < 2;                               // t_src = quad>>1 selector

    int mt0 = ks * 8;

    // prologue: zero EB; load adj for first tile
    f4 z = (f4){0.f, 0.f, 0.f, 0.f};
    #pragma unroll
    for (int k = 0; k < 4; k++) *(f4*)(&EBs[zr][zc0 + k * 4]) = z;

    f4 adjc[4];
    #pragma unroll
    for (int t = 0; t < 4; t++) {
        int col = mt0 * 64 + t * 16 + quad * 4;
        if (isf) {
            adjc[t] = *(const f4*)((const float*)adj + (long)(n0 + c) * 4096 + col);
        } else {
            ushort4 u = *(const ushort4*)((const u16*)adj + (long)(n0 + c) * 4096 + col);
            adjc[t] = (f4){bf2f(u.x), bf2f(u.y), bf2f(u.z), bf2f(u.w)};
        }
    }

    int bi0 = 0, bi1 = 0, tq = 0, has = 0;
    float ebv = 0.f;

    for (int rel = 0; rel < 8; rel++) {
        int mt = mt0 + rel;

        // batched csr load: one bptr->csr chain per 4 tiles
        if ((rel & 3) == 0) {
            int b = qt * 64 + mt;
            bi0 = bptr[b]; bi1 = bptr[b + 4];
            int ie = bi0 + lane;
            has = ie < bi1;
            tq = 0; ebv = 0.f;
            if (has) { tq = csr_tq[ie]; ebv = csr_b[(long)ie * 4 + h]; }
        }

        // edge scatter for THIS tile (operands in regs; sub-tile via tgt>>6)
        if (has && (((tq & 0xFFFF) >> 6) == mt))
            atomicAdd(&EBs[tq >> 16][tq & 63], ebv);
        if (bi1 > bi0 + 64) {                           // rare >64-edge tail
            for (int i = bi0 + 64 + lane; i < bi1; i += 64) {
                int tq2 = csr_tq[i];
                if (((tq2 & 0xFFFF) >> 6) == mt)
                    atomicAdd(&EBs[tq2 >> 16][tq2 & 63], csr_b[(long)i * 4 + h]);
            }
        }

        // S^T = (K·Q^T)*scale + 10*adj  (K from packed buffer: 1KB coalesced loads)
        float sv[4][4];
        #pragma unroll
        for (int t = 0; t < 4; t++) {
            f4 acc = (f4){0.f, 0.f, 0.f, 0.f};
            #pragma unroll
            for (int kw = 0; kw < 2; kw++) {
                bf8 kfr = *(const bf8*)(Kp + ((long)(((mt * 4 + h) * 4 + t) * 2 + kw) * 64 + lane) * 8);
                acc = __builtin_amdgcn_mfma_f32_16x16x32_bf16(kfr, qf[kw], acc, 0, 0, 0);
            }
            #pragma unroll
            for (int r = 0; r < 4; r++)
                sv[t][r] = acc[r] * SCALE + adjc[t][r] * 10.f;
        }

        // adjc consumed -> issue next tile's adj loads into the same registers
        if (rel < 7) {
            int m0n = (mt + 1) * 64;
            #pragma unroll
            for (int t = 0; t < 4; t++) {
                int col = m0n + t * 16 + quad * 4;
                if (isf) {
                    adjc[t] = *(const f4*)((const float*)adj + (long)(n0 + c) * 4096 + col);
                } else {
                    ushort4 u = *(const ushort4*)((const u16*)adj + (long)(n0 + c) * 4096 + col);
                    adjc[t] = (f4){bf2f(u.x), bf2f(u.y), bf2f(u.z), bf2f(u.w)};
                }
            }
        }

        // EB read (in-order behind scatter atomics), then re-zero for next tile
        #pragma unroll
        for (int t = 0; t < 4; t++) {
            f4 e = *(const f4*)(&EBs[c][t * 16 + quad * 4]);
            #pragma unroll
            for (int r = 0; r < 4; r++) sv[t][r] += e[r];
        }
        #pragma unroll
        for (int k = 0; k < 4; k++) *(f4*)(&EBs[zr][zc0 + k * 4]) = z;

        // no-max exp + bf16 pack: pw[2t+rp] = P[c][16t+4quad+2rp, +1]
        u32 pw[8];
        float s = 0.f;
        #pragma unroll
        for (int t = 0; t < 4; t++) {
            float p0 = __expf(sv[t][0]);
            float p1 = __expf(sv[t][1]);
            float p2 = __expf(sv[t][2]);
            float p3 = __expf(sv[t][3]);
            s += (p0 + p1) + (p2 + p3);
            pw[2 * t]     = (u32)f2bf(p0) | ((u32)f2bf(p1) << 16);
            pw[2 * t + 1] = (u32)f2bf(p2) | ((u32)f2bf(p3) << 16);
        }
        l_run += s;

        // in-register P shuffle -> PV A-fragments (16 bpermute + 8 cndmask, v7-proven)
        union PF { u32 w[4]; bf8 v; } pf0, pf1;
        {
            u32 a00 = (u32)__builtin_amdgcn_ds_bpermute(addrA, (int)pw[0]);
            u32 a10 = (u32)__builtin_amdgcn_ds_bpermute(addrA, (int)pw[2]);
            u32 a01 = (u32)__builtin_amdgcn_ds_bpermute(addrA, (int)pw[1]);
            u32 a11 = (u32)__builtin_amdgcn_ds_bpermute(addrA, (int)pw[3]);
            u32 b00 = (u32)__builtin_amdgcn_ds_bpermute(addrB, (int)pw[0]);
            u32 b10 = (u32)__builtin_amdgcn_ds_bpermute(addrB, (int)pw[2]);
            u32 b01 = (u32)__builtin_amdgcn_ds_bpermute(addrB, (int)pw[1]);
            u32 b11 = (u32)__builtin_amdgcn_ds_bpermute(addrB, (int)pw[3]);
            pf0.w[0] = selLo ? a00 : a10;
            pf0.w[1] = selLo ? a01 : a11;
            pf0.w[2] = selLo ? b00 : b10;
            pf0.w[3] = selLo ? b01 : b11;
            u32 c00 = (u32)__builtin_amdgcn_ds_bpermute(addrA, (int)pw[4]);
            u32 c10 = (u32)__builtin_amdgcn_ds_bpermute(addrA, (int)pw[6]);
            u32 c01 = (u32)__builtin_amdgcn_ds_bpermute(addrA, (int)pw[5]);
            u32 c11 = (u32)__builtin_amdgcn_ds_bpermute(addrA, (int)pw[7]);
            u32 d00 = (u32)__builtin_amdgcn_ds_bpermute(addrB, (int)pw[4]);
            u32 d10 = (u32)__builtin_amdgcn_ds_bpermute(addrB, (int)pw[6]);
            u32 d01 = (u32)__builtin_amdgcn_ds_bpermute(addrB, (int)pw[5]);
            u32 d11 = (u32)__builtin_amdgcn_ds_bpermute(addrB, (int)pw[7]);
            pf1.w[0] = selLo ? c00 : c10;
            pf1.w[1] = selLo ? c01 : c11;
            pf1.w[2] = selLo ? d00 : d10;
            pf1.w[3] = selLo ? d01 : d11;
        }

        // PV (V from packed buffer: 1KB coalesced loads)
        #pragma unroll
        for (int t = 0; t < 4; t++) {
            f4 o = Oacc[t];
            bf8 v0 = *(const bf8*)(Vp + ((long)(((mt * 4 + h) * 4 + t) * 2 + 0) * 64 + lane) * 8);
            o = __builtin_amdgcn_mfma_f32_16x16x32_bf16(pf0.v, v0, o, 0, 0, 0);
            bf8 v1 = *(const bf8*)(Vp + ((long)(((mt * 4 + h) * 4 + t) * 2 + 1) * 64 + lane) * 8);
            o = __builtin_amdgcn_mfma_f32_16x16x32_bf16(pf1.v, v1, o, 0, 0, 0);
            Oacc[t] = o;
        }
    }

    // final cross-quad row-sum for l (lanes c, c+16, c+32, c+48 share row c)
    l_run += __shfl_xor(l_run, 16);
    l_run += __shfl_xor(l_run, 32);

    // plain-sum merge into global f32 accumulators (fire-and-forget atomics)
    #pragma unroll
    for (int t = 0; t < 4; t++) {
        #pragma unroll
        for (int r = 0; r < 4; r++) {
            int q = quad * 4 + r;
            atomicAdd(&AOacc[(long)(n0 + q) * 256 + h * 64 + t * 16 + c], Oacc[t][r]);
        }
    }
    if (quad == 0)
        atomicAdd(&Lacc[(n0 + c) * 4 + h], l_run);
}

// ---------------- out-proj + bias + residual + LayerNorm (reduce fused in) ----------------
__global__ __launch_bounds__(256) void k_outln(
    const float* __restrict__ AOacc, const float* __restrict__ Lacc,
    const u16* __restrict__ WoT, const u16* __restrict__ SB,
    const void* __restrict__ Xin, const void* __restrict__ gv, const void* __restrict__ bv,
    void* __restrict__ out, const int* __restrict__ flag)
{
    __shared__ float Xl[16][257];
    __shared__ float ps[16][17], pss[16][17];
    __shared__ float mu_l[16], ri_l[16];
    int tid = threadIdx.x, wave = tid >> 6, lane = tid & 63, quad = lane >> 4, c = lane & 15;
    int m0 = blockIdx.x * 16;
    int isf = flag[0];

    int rowa = m0 + c;
    float l4[4];
    #pragma unroll
    for (int hh = 0; hh < 4; hh++) l4[hh] = Lacc[rowa * 4 + hh];

    bf8 af[8];
    #pragma unroll
    for (int ks = 0; ks < 8; ks++) {
        const float* pa = AOacc + (long)rowa * 256 + ks * 32 + quad * 8;
        f4 a = *(const f4*)pa, b = *(const f4*)(pa + 4);
        float L = l4[ks >> 1];
        bf8 t;
        #pragma unroll
        for (int j = 0; j < 4; j++) { t[j] = (short)f2bf(a[j] / L); t[j + 4] = (short)f2bf(b[j] / L); }
        af[ks] = t;
    }

    f4 acc[4];
    #pragma unroll
    for (int t = 0; t < 4; t++) acc[t] = (f4){0.f, 0.f, 0.f, 0.f};

    #pragma unroll
    for (int ks = 0; ks < 8; ks++) {
        #pragma unroll
        for (int t = 0; t < 4; t++) {
            bf8 bfr = *(const bf8*)(WoT + (wave * 64 + t * 16 + c) * 256 + ks * 32 + quad * 8);
            acc[t] = __builtin_amdgcn_mfma_f32_16x16x32_bf16(af[ks], bfr, acc[t], 0, 0, 0);
        }
    }
    #pragma unroll
    for (int t = 0; t < 4; t++) {
        int n = wave * 64 + t * 16 + c;
        float bb = bf2f(SB[3 * 256 + n]);   // bo
        #pragma unroll
        for (int r = 0; r < 4; r++) {
            int q = quad * 4 + r;
            float res = ldf(Xin, (long)(m0 + q) * 256 + n, isf);
            Xl[q][n] = acc[t][r] + bb + res;
        }
    }
    __syncthreads();
    int q = tid >> 4, i = tid & 15;
    float s = 0.f, ss = 0.f;
    #pragma unroll
    for (int j = 0; j < 16; j++) { float v = Xl[q][i * 16 + j]; s += v; ss += v * v; }
    ps[q][i] = s; pss[q][i] = ss;
    __syncthreads();
    if (tid < 16) {
        float s2 = 0.f, ss2 = 0.f;
        #pragma unroll
        for (int i2 = 0; i2 < 16; i2++) { s2 += ps[tid][i2]; ss2 += pss[tid][i2]; }
        float mu = s2 * (1.f / 256.f);
        float var = ss2 * (1.f / 256.f) - mu * mu;
        mu_l[tid] = mu;
        ri_l[tid] = rsqrtf(var + LN_EPS);
    }
    __syncthreads();
    float mu = mu_l[q], ri = ri_l[q];
    #pragma unroll
    for (int j = 0; j < 16; j++) {
        int n2 = i * 16 + j;
        float v = (Xl[q][n2] - mu) * ri;
        float g = ldf(gv, n2, isf), bt = ldf(bv, n2, isf);
        float y = g * v + bt;
        long oidx = (long)(m0 + q) * 256 + n2;
        if (isf) ((float*)out)[oidx] = y;      // output dtype follows input dtype
        else     ((u16*)out)[oidx] = f2bf(y);
    }
}

// ---------------- driver: 7 launches ----------------
extern "C" void kernel_launch(void* const* d_in, const int* in_sizes, int n_in,
                              void* d_out, int out_size, void* d_ws, size_t ws_size,
                              hipStream_t stream)
{
    const void* node = d_in[0];
    const void* adj  = d_in[1];
    const void* ef   = d_in[2];
    const int*  ei   = (const int*)d_in[3];
    const void* Wq = d_in[4];  const void* bq = d_in[5];
    const void* Wk = d_in[6];  const void* bk = d_in[7];
    const void* Wv = d_in[8];  const void* bv = d_in[9];
    const void* We = d_in[10]; const void* be = d_in[11];
    const void* Wo = d_in[12]; const void* bo = d_in[13];
    const void* gamma = d_in[14];
    const void* beta  = d_in[15];

    if (ws_size < WS_NEED) return;   // signature: output stays zero (absmax 4.81)

    char* ws = (char*)d_ws;
    u16*   WT     = (u16*)(ws + 0);          // 512 KB
    u16*   Qb     = (u16*)(ws + 524288);     // 2 MB bf16
    u16*   Kp     = (u16*)(ws + 2621440);    // 2 MB fragment-packed K
    u16*   Vp     = (u16*)(ws + 4718592);    // 2 MB fragment-packed V
    float* AOacc  = (float*)(ws + 6815744);  // 4 MB  f32[4096][256]
    float* Lacc   = (float*)(ws + 11010048); // 64 KB f32[4096][4]
    u16*   SB     = (u16*)(ws + 15728640);   // 4 KB
    int*   bcnt   = (int*)(ws + 15732736);   // 16384 + flag (65664 B)
    int*   flag   = bcnt + 16384;
    int*   bptr   = (int*)(ws + 15798400);   // int[16385] (65664 B)
    int*   csr_tq = (int*)(ws + 15864064);   // int[E] 512 KB
    float* csr_b  = (float*)(ws + 16388352); // float[E][4] 2 MB -> ends 18485504

    // 1. zero bcnt+flag (16416 ints) and AOacc+Lacc (1064960 floats)
    k_zero2<<<4225, 256, 0, stream>>>(bcnt, 16416, (int*)AOacc, 1064960);
    // 2. dtype detect || edge count
    k_detcnt<<<576, 256, 0, stream>>>((const u32*)node, 524288, flag, ei, bcnt);
    // 3. weight transpose || small-tensor cvt
    k_transpose<<<dim3(8, 8, 5), 256, 0, stream>>>(Wq, Wk, Wv, Wo, WT, flag,
                                                   bq, bk, bv, bo, gamma, beta, We, be, SB);
    // 4. bucket scan
    k_scan<<<1, 256, 0, stream>>>(bcnt, bptr, bcnt);
    // 5. QKV GEMM || edge fill
    k_qkvfill<<<768, 256, 0, stream>>>(node, WT, SB, Qb, Kp, Vp,
                                       ef, ei, bcnt, csr_tq, csr_b, flag);
    // 6. flash attention: 4-wave blocks, 20 waves/CU
    k_flash<<<dim3(256, 8), 256, 0, stream>>>(Qb, Kp, Vp, adj, bptr, csr_tq, csr_b,
                                              AOacc, Lacc, flag);
    // 7. out-proj + residual + LayerNorm (reduce fused)
    k_outln<<<256, 256, 0, stream>>>(AOacc, Lacc, WT + 3 * 65536, SB, node, gamma, beta,
                                     d_out, flag);
}

// Round 10
// 282.545 us; speedup vs baseline: 1.3427x; 1.3427x over previous
//
#include <hip/hip_runtime.h>
#include <hip/hip_bf16.h>

typedef unsigned short u16;
typedef unsigned int u32;
typedef __attribute__((ext_vector_type(8))) short bf8;   // 8 bf16 (4 VGPRs)
typedef __attribute__((ext_vector_type(4))) float f4;

#define SCALE 0.125f
#define LN_EPS 1e-5f
#define WS_NEED 18485504UL

__device__ __forceinline__ float bf2f(u16 u) {
    union { u32 i; float f; } x; x.i = ((u32)u) << 16; return x.f;
}
__device__ __forceinline__ u16 f2bf(float f) {
    union { u32 i; float f; } x; x.f = f;
    u32 i = x.i;
    return (u16)((i + 0x7FFFu + ((i >> 16) & 1u)) >> 16);   // RNE
}
__device__ __forceinline__ float ldf(const void* p, long i, int isf) {
    return isf ? ((const float*)p)[i] : bf2f(((const u16*)p)[i]);
}

// ---------------- fused zero: bcnt+flag range AND AOacc+Lacc range ----------------
__global__ void k_zero2(int* __restrict__ a, int na, int* __restrict__ b, int nb) {
    int i = blockIdx.x * 256 + threadIdx.x;
    if (i < na) a[i] = 0;
    else if (i - na < nb) b[i - na] = 0;
}

// ---------------- fused: dtype detect (blocks 0..63)  ||  edge count (blocks 64..575) ----------------
__global__ void k_detcnt(const u32* __restrict__ w, int nwords, int* __restrict__ flag,
                         const int* __restrict__ EI, int* __restrict__ bcnt) {
    int bx = blockIdx.x;
    if (bx < 64) {
        int hits = 0;
        for (int i = bx * 256 + threadIdx.x; i < nwords; i += 64 * 256) {
            u32 v = w[i];
            if (((v >> 7) & 0xFFu) == 0xFFu) hits++;
            if (((v >> 23) & 0xFFu) == 0xFFu) hits++;
        }
        if (hits) atomicOr(flag, 1);
    } else {
        int e = (bx - 64) * 256 + threadIdx.x;
        int src = EI[2 * e], tgt = EI[2 * e + 1];
        atomicAdd(&bcnt[(src >> 4) * 64 + (tgt >> 6)], 1);
    }
}

// ---------------- weight transpose (z<4)  ||  small-tensor cvt (z==4) ----------------
// SB (u16): [bq 256][bk 256][bv 256][bo 256][gamma 256][beta 256][We 256][be 4]
__global__ __launch_bounds__(256) void k_transpose(const void* __restrict__ Wq,
    const void* __restrict__ Wk, const void* __restrict__ Wv, const void* __restrict__ Wo,
    u16* __restrict__ out, const int* __restrict__ flag,
    const void* bq, const void* bk, const void* bv, const void* bo,
    const void* g, const void* bt, const void* We, const void* be, u16* __restrict__ SB)
{
    __shared__ u16 tile[32][33];
    int isf = flag[0];
    if (blockIdx.z == 4) {
        if (blockIdx.x == 0 && blockIdx.y == 0) {
            int t = threadIdx.x;
            SB[0 * 256 + t] = isf ? f2bf(((const float*)bq)[t]) : ((const u16*)bq)[t];
            SB[1 * 256 + t] = isf ? f2bf(((const float*)bk)[t]) : ((const u16*)bk)[t];
            SB[2 * 256 + t] = isf ? f2bf(((const float*)bv)[t]) : ((const u16*)bv)[t];
            SB[3 * 256 + t] = isf ? f2bf(((const float*)bo)[t]) : ((const u16*)bo)[t];
            SB[4 * 256 + t] = isf ? f2bf(((const float*)g)[t])  : ((const u16*)g)[t];
            SB[5 * 256 + t] = isf ? f2bf(((const float*)bt)[t]) : ((const u16*)bt)[t];
            SB[6 * 256 + t] = isf ? f2bf(((const float*)We)[t]) : ((const u16*)We)[t];
            if (t < 4)
                SB[7 * 256 + t] = isf ? f2bf(((const float*)be)[t]) : ((const u16*)be)[t];
        }
        return;
    }
    const void* src = blockIdx.z == 0 ? Wq : blockIdx.z == 1 ? Wk : blockIdx.z == 2 ? Wv : Wo;
    u16* dst = out + blockIdx.z * 65536;
    int r0 = blockIdx.x * 32, c0 = blockIdx.y * 32;
    int lr = threadIdx.x >> 5, lc = threadIdx.x & 31;
    #pragma unroll
    for (int rr = 0; rr < 4; rr++) {
        int r = rr * 8 + lr;
        long idx = (long)(r0 + r) * 256 + c0 + lc;
        tile[r][lc] = isf ? f2bf(((const float*)src)[idx]) : ((const u16*)src)[idx];
    }
    __syncthreads();
    #pragma unroll
    for (int rr = 0; rr < 4; rr++) {
        int r = rr * 8 + lr;
        dst[(c0 + r) * 256 + r0 + lc] = tile[lc][r];
    }
}

// ---------------- scan (unchanged) ----------------
__global__ __launch_bounds__(256) void k_scan(const int* __restrict__ cntin,
                                              int* __restrict__ bptr, int* __restrict__ nextc)
{
    __shared__ int tot[256], base_l[256];
    int tid = threadIdx.x;
    int s = 0;
    int loc[64];
    #pragma unroll
    for (int j = 0; j < 64; j++) { loc[j] = cntin[tid * 64 + j]; s += loc[j]; }
    tot[tid] = s;
    __syncthreads();
    if (tid == 0) {
        int run = 0;
        for (int i = 0; i < 256; i++) { int t = tot[i]; base_l[i] = run; run += t; }
        bptr[16384] = run;
    }
    __syncthreads();
    int b = base_l[tid];
    #pragma unroll
    for (int j = 0; j < 64; j++) { bptr[tid * 64 + j] = b; nextc[tid * 64 + j] = b; b += loc[j]; }
}

// ---------------- fused: QKV GEMM (blocks 0..255)  ||  edge fill (blocks 256..767) ----------------
// Packed layouts (v8-proven; flash loads become single 1KB coalesced reads):
//   Kp[((((mt*4+h)*4+tk)*2+kw)*64 + q*16+ck)*8 + j]  <- K[row= mt*64+tk*16+ck][col= h*64+kw*32+q*8+j]
//   Vp[((((mt*4+h)*4+t2)*2+hf)*64 + q*16+c2)*8 + j]  <- V[node m= mt*64+hf*32+q*8+j][dim d= h*64+t2*16+c2]
__global__ __launch_bounds__(256) void k_qkvfill(const void* __restrict__ X,
    const u16* __restrict__ WT, const u16* __restrict__ SB,
    u16* __restrict__ Qo, u16* __restrict__ Kp, u16* __restrict__ Vp,
    const void* __restrict__ EF, const int* __restrict__ EI,
    int* __restrict__ nextc, int* __restrict__ csr_tq, float* __restrict__ csr_b,
    const int* __restrict__ flag)
{
    __shared__ float Wl[64][4];
    __shared__ float bel[4];
    int tid = threadIdx.x;
    int isf = flag[0];

    if (blockIdx.x < 256) {
        // ---- QKV GEMM (v8 body) ----
        int wave = tid >> 6, lane = tid & 63, quad = lane >> 4, c = lane & 15;
        int m0 = blockIdx.x * 16;

        bf8 af[8];
        if (isf) {
            const float* Xf = (const float*)X;
            #pragma unroll
            for (int ks = 0; ks < 8; ks++) {
                const float* p = Xf + (long)(m0 + c) * 256 + ks * 32 + quad * 8;
                f4 a = *(const f4*)p, b = *(const f4*)(p + 4);
                bf8 t;
                #pragma unroll
                for (int j = 0; j < 4; j++) { t[j] = (short)f2bf(a[j]); t[j + 4] = (short)f2bf(b[j]); }
                af[ks] = t;
            }
        } else {
            #pragma unroll
            for (int ks = 0; ks < 8; ks++)
                af[ks] = *(const bf8*)((const u16*)X + (long)(m0 + c) * 256 + ks * 32 + quad * 8);
        }

        for (int which = 0; which < 3; which++) {
            const u16* Wp = WT + which * 65536;
            const u16* bias = SB + which * 256;

            f4 acc[4];
            #pragma unroll
            for (int t = 0; t < 4; t++) acc[t] = (f4){0.f, 0.f, 0.f, 0.f};

            #pragma unroll
            for (int ks = 0; ks < 8; ks++) {
                #pragma unroll
                for (int t = 0; t < 4; t++) {
                    bf8 bfr = *(const bf8*)(Wp + (wave * 64 + t * 16 + c) * 256 + ks * 32 + quad * 8);
                    acc[t] = __builtin_amdgcn_mfma_f32_16x16x32_bf16(af[ks], bfr, acc[t], 0, 0, 0);
                }
            }
            #pragma unroll
            for (int t = 0; t < 4; t++) {
                int n = wave * 64 + t * 16 + c;
                float bb = bf2f(bias[n]);
                #pragma unroll
                for (int r = 0; r < 4; r++) {
                    int row = m0 + quad * 4 + r;
                    float v = acc[t][r] + bb;
                    u16 bv16 = f2bf(v);
                    if (which == 0) {
                        Qo[(long)row * 256 + n] = bv16;
                    } else if (which == 1) {
                        int mt = row >> 6, tk = (row >> 4) & 3, ck = row & 15;
                        int hh = n >> 6, kw = (n >> 5) & 1, q = (n >> 3) & 3, j = n & 7;
                        long idx = ((long)(((mt * 4 + hh) * 4 + tk) * 2 + kw) * 64 + q * 16 + ck) * 8 + j;
                        Kp[idx] = bv16;
                    } else {
                        int hh = n >> 6, t2 = (n >> 4) & 3, c2 = n & 15;
                        int mt = row >> 6, mo = row & 63, hf = mo >> 5, q = (mo >> 3) & 3, j = mo & 7;
                        long idx = ((long)(((mt * 4 + hh) * 4 + t2) * 2 + hf) * 64 + q * 16 + c2) * 8 + j;
                        Vp[idx] = bv16;
                    }
                }
            }
        }
    } else {
        // ---- edge-bias GEMV + bucketed fill (proven body) ----
        Wl[tid >> 2][tid & 3] = bf2f(SB[6 * 256 + tid]);
        if (tid < 4) bel[tid] = bf2f(SB[7 * 256 + tid]);
        __syncthreads();
        int e = (blockIdx.x - 256) * 256 + tid;
        int src = EI[2 * e], tgt = EI[2 * e + 1];
        float ea0 = bel[0], ea1 = bel[1], ea2 = bel[2], ea3 = bel[3];
        if (isf) {
            const float* Ff = (const float*)EF + (long)e * 64;
            for (int d0 = 0; d0 < 64; d0 += 4) {
                f4 v = *(const f4*)(Ff + d0);
                #pragma unroll
                for (int j = 0; j < 4; j++) {
                    float f = v[j];
                    ea0 += f * Wl[d0 + j][0];
                    ea1 += f * Wl[d0 + j][1];
                    ea2 += f * Wl[d0 + j][2];
                    ea3 += f * Wl[d0 + j][3];
                }
            }
        } else {
            const u16* Fb = (const u16*)EF + (long)e * 64;
            for (int d0 = 0; d0 < 64; d0 += 8) {
                bf8 v8 = *(const bf8*)(Fb + d0);
                #pragma unroll
                for (int j = 0; j < 8; j++) {
                    float f = bf2f((u16)v8[j]);
                    ea0 += f * Wl[d0 + j][0];
                    ea1 += f * Wl[d0 + j][1];
                    ea2 += f * Wl[d0 + j][2];
                    ea3 += f * Wl[d0 + j][3];
                }
            }
        }
        int bucket = (src >> 4) * 64 + (tgt >> 6);
        int pos = atomicAdd(&nextc[bucket], 1);
        csr_tq[pos] = ((src & 15) << 16) | tgt;
        f4 bb = {ea0, ea1, ea2, ea3};
        *(f4*)(csr_b + (long)pos * 4) = bb;
    }
}

// ---------------- flash: EXACT v8 body/config (R7-proven 93us local optimum) ----------------
// grid (qt=256, h=4, ks=4), 1-wave blocks, launch_bounds(64,4). Packed K/V 1KB
// coalesced loads, adj consume-then-reload lookahead, csr batched per 4 tiles,
// bpermute P-shuffle (no P LDS round-trip), no-max softmax, f32 atomic merge.
// R8 K-prefetch REVERTED (spill: VGPR 56->64, WRITE +2MB, 93->108us).
// R9/R10 multi-wave packaging REVERTED (spill at every reachable reg cap).
__global__ __launch_bounds__(64, 4) void k_flash(
    const u16* __restrict__ Qb, const u16* __restrict__ Kp, const u16* __restrict__ Vp,
    const void* __restrict__ adj, const int* __restrict__ bptr,
    const int* __restrict__ csr_tq, const float* __restrict__ csr_b,
    float* __restrict__ AOacc, float* __restrict__ Lacc, const int* __restrict__ flag)
{
    __shared__ alignas(16) float EBs[16][68];          // 4352 B, single buffer

    int lane = threadIdx.x, quad = lane >> 4, c = lane & 15;
    int qt = blockIdx.x, h = blockIdx.y, ks = blockIdx.z;
    int n0 = qt * 16;
    int isf = flag[0];

    // Q fragments (B-operand of swapped QK^T): row n0+c, k = h*64 + kw*32 + quad*8
    bf8 qf[2];
    #pragma unroll
    for (int kw = 0; kw < 2; kw++)
        qf[kw] = *(const bf8*)(Qb + (long)(n0 + c) * 256 + h * 64 + kw * 32 + quad * 8);

    float l_run = 0.f;
    f4 Oacc[4];
    #pragma unroll
    for (int t = 0; t < 4; t++) Oacc[t] = (f4){0.f, 0.f, 0.f, 0.f};

    int zr = lane >> 2, zc0 = (lane & 3) * 16;          // EB zeroing assignment
    // bpermute byte addresses (lane-constant): srcLane = quad_src*16 + c
    int addrA = ((2 * (quad & 1)) * 16 + c) * 4;        // i in {0,1}
    int addrB = addrA + 64;                             // i in {2,3} (+16 lanes)
    int selLo = quad < 2;                               // t_src = quad>>1 selector

    int mt0 = ks * 16;

    // prologue: zero EB; load adj for first tile
    f4 z = (f4){0.f, 0.f, 0.f, 0.f};
    #pragma unroll
    for (int k = 0; k < 4; k++) *(f4*)(&EBs[zr][zc0 + k * 4]) = z;

    f4 adjc[4];
    #pragma unroll
    for (int t = 0; t < 4; t++) {
        int col = mt0 * 64 + t * 16 + quad * 4;
        if (isf) {
            adjc[t] = *(const f4*)((const float*)adj + (long)(n0 + c) * 4096 + col);
        } else {
            ushort4 u = *(const ushort4*)((const u16*)adj + (long)(n0 + c) * 4096 + col);
            adjc[t] = (f4){bf2f(u.x), bf2f(u.y), bf2f(u.z), bf2f(u.w)};
        }
    }

    int bi0 = 0, bi1 = 0, tq = 0, has = 0;
    float ebv = 0.f;

    for (int rel = 0; rel < 16; rel++) {
        int mt = mt0 + rel;

        // batched csr load: one bptr->csr chain per 4 tiles
        if ((rel & 3) == 0) {
            int b = qt * 64 + mt;
            bi0 = bptr[b]; bi1 = bptr[b + 4];
            int ie = bi0 + lane;
            has = ie < bi1;
            tq = 0; ebv = 0.f;
            if (has) { tq = csr_tq[ie]; ebv = csr_b[(long)ie * 4 + h]; }
        }

        // edge scatter for THIS tile (operands in regs; sub-tile via tgt>>6)
        if (has && (((tq & 0xFFFF) >> 6) == mt))
            atomicAdd(&EBs[tq >> 16][tq & 63], ebv);
        if (bi1 > bi0 + 64) {                           // rare >64-edge tail
            for (int i = bi0 + 64 + lane; i < bi1; i += 64) {
                int tq2 = csr_tq[i];
                if (((tq2 & 0xFFFF) >> 6) == mt)
                    atomicAdd(&EBs[tq2 >> 16][tq2 & 63], csr_b[(long)i * 4 + h]);
            }
        }

        // S^T = (K·Q^T)*scale + 10*adj  (K from packed buffer: 1KB coalesced loads)
        float sv[4][4];
        #pragma unroll
        for (int t = 0; t < 4; t++) {
            f4 acc = (f4){0.f, 0.f, 0.f, 0.f};
            #pragma unroll
            for (int kw = 0; kw < 2; kw++) {
                bf8 kfr = *(const bf8*)(Kp + ((long)(((mt * 4 + h) * 4 + t) * 2 + kw) * 64 + lane) * 8);
                acc = __builtin_amdgcn_mfma_f32_16x16x32_bf16(kfr, qf[kw], acc, 0, 0, 0);
            }
            #pragma unroll
            for (int r = 0; r < 4; r++)
                sv[t][r] = acc[r] * SCALE + adjc[t][r] * 10.f;
        }

        // adjc consumed -> issue next tile's adj loads into the same registers
        if (rel < 15) {
            int m0n = (mt + 1) * 64;
            #pragma unroll
            for (int t = 0; t < 4; t++) {
                int col = m0n + t * 16 + quad * 4;
                if (isf) {
                    adjc[t] = *(const f4*)((const float*)adj + (long)(n0 + c) * 4096 + col);
                } else {
                    ushort4 u = *(const ushort4*)((const u16*)adj + (long)(n0 + c) * 4096 + col);
                    adjc[t] = (f4){bf2f(u.x), bf2f(u.y), bf2f(u.z), bf2f(u.w)};
                }
            }
        }

        // EB read (in-order behind scatter atomics), then re-zero for next tile
        #pragma unroll
        for (int t = 0; t < 4; t++) {
            f4 e = *(const f4*)(&EBs[c][t * 16 + quad * 4]);
            #pragma unroll
            for (int r = 0; r < 4; r++) sv[t][r] += e[r];
        }
        #pragma unroll
        for (int k = 0; k < 4; k++) *(f4*)(&EBs[zr][zc0 + k * 4]) = z;

        // no-max exp + bf16 pack: pw[2t+rp] = P[c][16t+4quad+2rp, +1]
        u32 pw[8];
        float s = 0.f;
        #pragma unroll
        for (int t = 0; t < 4; t++) {
            float p0 = __expf(sv[t][0]);
            float p1 = __expf(sv[t][1]);
            float p2 = __expf(sv[t][2]);
            float p3 = __expf(sv[t][3]);
            s += (p0 + p1) + (p2 + p3);
            pw[2 * t]     = (u32)f2bf(p0) | ((u32)f2bf(p1) << 16);
            pw[2 * t + 1] = (u32)f2bf(p2) | ((u32)f2bf(p3) << 16);
        }
        l_run += s;

        // in-register P shuffle -> PV A-fragments (16 bpermute + 8 cndmask, v7-proven)
        union PF { u32 w[4]; bf8 v; } pf0, pf1;
        {
            u32 a00 = (u32)__builtin_amdgcn_ds_bpermute(addrA, (int)pw[0]);
            u32 a10 = (u32)__builtin_amdgcn_ds_bpermute(addrA, (int)pw[2]);
            u32 a01 = (u32)__builtin_amdgcn_ds_bpermute(addrA, (int)pw[1]);
            u32 a11 = (u32)__builtin_amdgcn_ds_bpermute(addrA, (int)pw[3]);
            u32 b00 = (u32)__builtin_amdgcn_ds_bpermute(addrB, (int)pw[0]);
            u32 b10 = (u32)__builtin_amdgcn_ds_bpermute(addrB, (int)pw[2]);
            u32 b01 = (u32)__builtin_amdgcn_ds_bpermute(addrB, (int)pw[1]);
            u32 b11 = (u32)__builtin_amdgcn_ds_bpermute(addrB, (int)pw[3]);
            pf0.w[0] = selLo ? a00 : a10;
            pf0.w[1] = selLo ? a01 : a11;
            pf0.w[2] = selLo ? b00 : b10;
            pf0.w[3] = selLo ? b01 : b11;
            u32 c00 = (u32)__builtin_amdgcn_ds_bpermute(addrA, (int)pw[4]);
            u32 c10 = (u32)__builtin_amdgcn_ds_bpermute(addrA, (int)pw[6]);
            u32 c01 = (u32)__builtin_amdgcn_ds_bpermute(addrA, (int)pw[5]);
            u32 c11 = (u32)__builtin_amdgcn_ds_bpermute(addrA, (int)pw[7]);
            u32 d00 = (u32)__builtin_amdgcn_ds_bpermute(addrB, (int)pw[4]);
            u32 d10 = (u32)__builtin_amdgcn_ds_bpermute(addrB, (int)pw[6]);
            u32 d01 = (u32)__builtin_amdgcn_ds_bpermute(addrB, (int)pw[5]);
            u32 d11 = (u32)__builtin_amdgcn_ds_bpermute(addrB, (int)pw[7]);
            pf1.w[0] = selLo ? c00 : c10;
            pf1.w[1] = selLo ? c01 : c11;
            pf1.w[2] = selLo ? d00 : d10;
            pf1.w[3] = selLo ? d01 : d11;
        }

        // PV (V from packed buffer: 1KB coalesced loads)
        #pragma unroll
        for (int t = 0; t < 4; t++) {
            f4 o = Oacc[t];
            bf8 v0 = *(const bf8*)(Vp + ((long)(((mt * 4 + h) * 4 + t) * 2 + 0) * 64 + lane) * 8);
            o = __builtin_amdgcn_mfma_f32_16x16x32_bf16(pf0.v, v0, o, 0, 0, 0);
            bf8 v1 = *(const bf8*)(Vp + ((long)(((mt * 4 + h) * 4 + t) * 2 + 1) * 64 + lane) * 8);
            o = __builtin_amdgcn_mfma_f32_16x16x32_bf16(pf1.v, v1, o, 0, 0, 0);
            Oacc[t] = o;
        }
    }

    // final cross-quad row-sum for l (lanes c, c+16, c+32, c+48 share row c)
    l_run += __shfl_xor(l_run, 16);
    l_run += __shfl_xor(l_run, 32);

    // plain-sum merge into global f32 accumulators (fire-and-forget atomics)
    #pragma unroll
    for (int t = 0; t < 4; t++) {
        #pragma unroll
        for (int r = 0; r < 4; r++) {
            int q = quad * 4 + r;
            atomicAdd(&AOacc[(long)(n0 + q) * 256 + h * 64 + t * 16 + c], Oacc[t][r]);
        }
    }
    if (quad == 0)
        atomicAdd(&Lacc[(n0 + c) * 4 + h], l_run);
}

// ---------------- out-proj + bias + residual + LayerNorm (reduce fused in) ----------------
__global__ __launch_bounds__(256) void k_outln(
    const float* __restrict__ AOacc, const float* __restrict__ Lacc,
    const u16* __restrict__ WoT, const u16* __restrict__ SB,
    const void* __restrict__ Xin, const void* __restrict__ gv, const void* __restrict__ bv,
    void* __restrict__ out, const int* __restrict__ flag)
{
    __shared__ float Xl[16][257];
    __shared__ float ps[16][17], pss[16][17];
    __shared__ float mu_l[16], ri_l[16];
    int tid = threadIdx.x, wave = tid >> 6, lane = tid & 63, quad = lane >> 4, c = lane & 15;
    int m0 = blockIdx.x * 16;
    int isf = flag[0];

    int rowa = m0 + c;
    float l4[4];
    #pragma unroll
    for (int hh = 0; hh < 4; hh++) l4[hh] = Lacc[rowa * 4 + hh];

    bf8 af[8];
    #pragma unroll
    for (int ks = 0; ks < 8; ks++) {
        const float* pa = AOacc + (long)rowa * 256 + ks * 32 + quad * 8;
        f4 a = *(const f4*)pa, b = *(const f4*)(pa + 4);
        float L = l4[ks >> 1];
        bf8 t;
        #pragma unroll
        for (int j = 0; j < 4; j++) { t[j] = (short)f2bf(a[j] / L); t[j + 4] = (short)f2bf(b[j] / L); }
        af[ks] = t;
    }

    f4 acc[4];
    #pragma unroll
    for (int t = 0; t < 4; t++) acc[t] = (f4){0.f, 0.f, 0.f, 0.f};

    #pragma unroll
    for (int ks = 0; ks < 8; ks++) {
        #pragma unroll
        for (int t = 0; t < 4; t++) {
            bf8 bfr = *(const bf8*)(WoT + (wave * 64 + t * 16 + c) * 256 + ks * 32 + quad * 8);
            acc[t] = __builtin_amdgcn_mfma_f32_16x16x32_bf16(af[ks], bfr, acc[t], 0, 0, 0);
        }
    }
    #pragma unroll
    for (int t = 0; t < 4; t++) {
        int n = wave * 64 + t * 16 + c;
        float bb = bf2f(SB[3 * 256 + n]);   // bo
        #pragma unroll
        for (int r = 0; r < 4; r++) {
            int q = quad * 4 + r;
            float res = ldf(Xin, (long)(m0 + q) * 256 + n, isf);
            Xl[q][n] = acc[t][r] + bb + res;
        }
    }
    __syncthreads();
    int q = tid >> 4, i = tid & 15;
    float s = 0.f, ss = 0.f;
    #pragma unroll
    for (int j = 0; j < 16; j++) { float v = Xl[q][i * 16 + j]; s += v; ss += v * v; }
    ps[q][i] = s; pss[q][i] = ss;
    __syncthreads();
    if (tid < 16) {
        float s2 = 0.f, ss2 = 0.f;
        #pragma unroll
        for (int i2 = 0; i2 < 16; i2++) { s2 += ps[tid][i2]; ss2 += pss[tid][i2]; }
        float mu = s2 * (1.f / 256.f);
        float var = ss2 * (1.f / 256.f) - mu * mu;
        mu_l[tid] = mu;
        ri_l[tid] = rsqrtf(var + LN_EPS);
    }
    __syncthreads();
    float mu = mu_l[q], ri = ri_l[q];
    #pragma unroll
    for (int j = 0; j < 16; j++) {
        int n2 = i * 16 + j;
        float v = (Xl[q][n2] - mu) * ri;
        float g = ldf(gv, n2, isf), bt = ldf(bv, n2, isf);
        float y = g * v + bt;
        long oidx = (long)(m0 + q) * 256 + n2;
        if (isf) ((float*)out)[oidx] = y;      // output dtype follows input dtype
        else     ((u16*)out)[oidx] = f2bf(y);
    }
}

// ---------------- driver: 7 launches ----------------
extern "C" void kernel_launch(void* const* d_in, const int* in_sizes, int n_in,
                              void* d_out, int out_size, void* d_ws, size_t ws_size,
                              hipStream_t stream)
{
    const void* node = d_in[0];
    const void* adj  = d_in[1];
    const void* ef   = d_in[2];
    const int*  ei   = (const int*)d_in[3];
    const void* Wq = d_in[4];  const void* bq = d_in[5];
    const void* Wk = d_in[6];  const void* bk = d_in[7];
    const void* Wv = d_in[8];  const void* bv = d_in[9];
    const void* We = d_in[10]; const void* be = d_in[11];
    const void* Wo = d_in[12]; const void* bo = d_in[13];
    const void* gamma = d_in[14];
    const void* beta  = d_in[15];

    if (ws_size < WS_NEED) return;   // signature: output stays zero (absmax 4.81)

    char* ws = (char*)d_ws;
    u16*   WT     = (u16*)(ws + 0);          // 512 KB
    u16*   Qb     = (u16*)(ws + 524288);     // 2 MB bf16
    u16*   Kp     = (u16*)(ws + 2621440);    // 2 MB fragment-packed K
    u16*   Vp     = (u16*)(ws + 4718592);    // 2 MB fragment-packed V
    float* AOacc  = (float*)(ws + 6815744);  // 4 MB  f32[4096][256]
    float* Lacc   = (float*)(ws + 11010048); // 64 KB f32[4096][4]
    u16*   SB     = (u16*)(ws + 15728640);   // 4 KB
    int*   bcnt   = (int*)(ws + 15732736);   // 16384 + flag (65664 B)
    int*   flag   = bcnt + 16384;
    int*   bptr   = (int*)(ws + 15798400);   // int[16385] (65664 B)
    int*   csr_tq = (int*)(ws + 15864064);   // int[E] 512 KB
    float* csr_b  = (float*)(ws + 16388352); // float[E][4] 2 MB -> ends 18485504

    // 1. zero bcnt+flag (16416 ints) and AOacc+Lacc (1064960 floats)
    k_zero2<<<4225, 256, 0, stream>>>(bcnt, 16416, (int*)AOacc, 1064960);
    // 2. dtype detect || edge count
    k_detcnt<<<576, 256, 0, stream>>>((const u32*)node, 524288, flag, ei, bcnt);
    // 3. weight transpose || small-tensor cvt
    k_transpose<<<dim3(8, 8, 5), 256, 0, stream>>>(Wq, Wk, Wv, Wo, WT, flag,
                                                   bq, bk, bv, bo, gamma, beta, We, be, SB);
    // 4. bucket scan
    k_scan<<<1, 256, 0, stream>>>(bcnt, bptr, bcnt);
    // 5. QKV GEMM || edge fill
    k_qkvfill<<<768, 256, 0, stream>>>(node, WT, SB, Qb, Kp, Vp,
                                       ef, ei, bcnt, csr_tq, csr_b, flag);
    // 6. flash attention (exact v8: 1-wave blocks, ks=4, 16 tiles/wave)
    k_flash<<<dim3(256, 4, 4), 64, 0, stream>>>(Qb, Kp, Vp, adj, bptr, csr_tq, csr_b,
                                                AOacc, Lacc, flag);
    // 7. out-proj + residual + LayerNorm (reduce fused)
    k_outln<<<256, 256, 0, stream>>>(AOacc, Lacc, WT + 3 * 65536, SB, node, gamma, beta,
                                     d_out, flag);
}